// Round 8
// baseline (389.021 us; speedup 1.0000x reference)
//
#include <hip/hip_runtime.h>
#include <hip/hip_bf16.h>

#define D 128            // D_IN == D_OUT
#define NSLICE 8         // 8 col-slices of 16 cols (32 B bf16 per row-slice)

typedef __attribute__((ext_vector_type(8))) short  short8;
typedef __attribute__((ext_vector_type(4))) float  f32x4;
typedef __attribute__((ext_vector_type(2))) float  f32x2;

// fp32 -> bf16 (RTNE)
__device__ __forceinline__ unsigned f2bf(float f) {
    unsigned u = __float_as_uint(f);
    u += 0x7FFFu + ((u >> 16) & 1u);
    return u >> 16;
}
__device__ __forceinline__ unsigned pk2(float a, float b) {
    return f2bf(a) | (f2bf(b) << 16);
}
__device__ __forceinline__ float bflo(unsigned u) { return __uint_as_float(u << 16); }
__device__ __forceinline__ float bfhi(unsigned u) { return __uint_as_float(u & 0xFFFF0000u); }

// ---------------------------------------------------------------------------
// Kernel 1: y = bf16(x @ W) via MFMA 16x16x32 bf16.
// SLICE-MAJOR y store: y[ct][node][16 cols] (ct = 16-col tile = slice).
// Still one coalesced 512 B store per (tile, ct).
// ---------------------------------------------------------------------------
__global__ __launch_bounds__(256, 2) void gemm_mfma_kernel(
    const float* __restrict__ x, const float* __restrict__ W,
    unsigned* __restrict__ y, int n_nodes, int ntiles)
{
    __shared__ unsigned short Wt[D * D];   // bf16 [c][k], k XOR-swizzled, 32 KB

    const int t = threadIdx.x;
    const size_t NN = (size_t)n_nodes;

    {
        const float4* W4 = reinterpret_cast<const float4*>(W);
#pragma unroll
        for (int m = 0; m < 16; ++m) {
            const int idx4 = m * 256 + t;        // float4 index
            const int k  = idx4 >> 5;            // 32 float4 per k-row
            const int c0 = (idx4 & 31) << 2;
            const float4 w = W4[idx4];
            const float wv[4] = {w.x, w.y, w.z, w.w};
#pragma unroll
            for (int i = 0; i < 4; ++i) {
                const int c    = c0 + i;
                const int slot = (k >> 3) ^ (c & 15);
                Wt[c * 128 + slot * 8 + (k & 7)] = (unsigned short)f2bf(wv[i]);
            }
        }
    }
    __syncthreads();

    const int lane = t & 63;
    const int cl   = lane & 15;
    const int g    = lane >> 4;

    short8 wf[8][4];
#pragma unroll
    for (int ct = 0; ct < 8; ++ct)
#pragma unroll
        for (int ks = 0; ks < 4; ++ks) {
            const int c    = ct * 16 + cl;
            const int slot = (ks * 4 + g) ^ cl;
            wf[ct][ks] = *reinterpret_cast<const short8*>(&Wt[c * 128 + slot * 8]);
        }

    const int wave   = (blockIdx.x << 2) | (t >> 6);
    const int nwaves = gridDim.x << 2;

#define LOADX(rt_, buf_)                                                      \
    {                                                                         \
        int r_ = (rt_) * 16 + cl;                                             \
        if (r_ >= n_nodes) r_ = n_nodes - 1;                                  \
        const float* p_ = x + (size_t)r_ * D + g * 8;                         \
        _Pragma("unroll")                                                     \
        for (int ks_ = 0; ks_ < 4; ++ks_) {                                   \
            buf_[2 * ks_]     = *reinterpret_cast<const float4*>(p_ + ks_ * 32);     \
            buf_[2 * ks_ + 1] = *reinterpret_cast<const float4*>(p_ + ks_ * 32 + 4); \
        }                                                                     \
    }

#define COMPUTE(rt_, buf_)                                                    \
    {                                                                         \
        f32x4 acc_[8];                                                        \
        _Pragma("unroll")                                                     \
        for (int ct_ = 0; ct_ < 8; ++ct_) acc_[ct_] = (f32x4)(0.f);           \
        _Pragma("unroll")                                                     \
        for (int ks_ = 0; ks_ < 4; ++ks_) {                                   \
            short8 xf_;                                                       \
            unsigned* xu_ = reinterpret_cast<unsigned*>(&xf_);                \
            const float4 a_ = buf_[2 * ks_], b_ = buf_[2 * ks_ + 1];          \
            xu_[0] = pk2(a_.x, a_.y); xu_[1] = pk2(a_.z, a_.w);               \
            xu_[2] = pk2(b_.x, b_.y); xu_[3] = pk2(b_.z, b_.w);               \
            _Pragma("unroll")                                                 \
            for (int ct_ = 0; ct_ < 8; ++ct_)                                 \
                acc_[ct_] = __builtin_amdgcn_mfma_f32_16x16x32_bf16(          \
                    wf[ct_][ks_], xf_, acc_[ct_], 0, 0, 0);                   \
        }                                                                     \
        const int r_ = (rt_) * 16 + cl;                                       \
        if (r_ < n_nodes) {                                                   \
            _Pragma("unroll")                                                 \
            for (int ct_ = 0; ct_ < 8; ++ct_) {                               \
                uint2 v2_ = make_uint2(pk2(acc_[ct_][0], acc_[ct_][1]),       \
                                       pk2(acc_[ct_][2], acc_[ct_][3]));      \
                unsigned* yp_ = y + ((size_t)ct_ * NN + r_) * 8 + g * 2;      \
                *reinterpret_cast<uint2*>(yp_) = v2_;                         \
            }                                                                 \
        }                                                                     \
    }

    int rt = wave;
    if (rt >= ntiles) return;
    float4 bufA[8], bufB[8];
    LOADX(rt, bufA);
    while (true) {
        int nxt = rt + nwaves;
        if (nxt < ntiles) {
            LOADX(nxt, bufB);
            COMPUTE(rt, bufA);
            rt = nxt;
            nxt = rt + nwaves;
            if (nxt < ntiles) {
                LOADX(nxt, bufA);
                COMPUTE(rt, bufB);
                rt = nxt;
            } else { COMPUTE(rt, bufB); break; }
        } else { COMPUTE(rt, bufA); break; }
    }
#undef LOADX
#undef COMPUTE
}

// ---------------------------------------------------------------------------
// Kernel 2: build CSR row_ptr from sorted edge_row.
// ---------------------------------------------------------------------------
__global__ __launch_bounds__(256) void build_rowptr_kernel(
    const int* __restrict__ row, int* __restrict__ ptr, int n_edges, int n_nodes)
{
    int e = blockIdx.x * blockDim.x + threadIdx.x;
    if (e > n_edges) return;
    int lo, hi;                     // set ptr[r] = e for r in (lo, hi]
    if (e == 0)            { lo = -1;               hi = row[0];   }
    else if (e == n_edges) { lo = row[n_edges - 1]; hi = n_nodes;  }
    else {
        lo = row[e - 1];
        hi = row[e];
        if (lo == hi) return;
    }
    for (int r = lo + 1; r <= hi; ++r) ptr[r] = e;
}

// ---------------------------------------------------------------------------
// Kernel 3: col-sliced, XCD-pinned SpMM.
// pass = blockIdx & 7  -> with round-robin block->XCD dispatch, each XCD
// works on ONE 3.2 MB y-slice forever => slice is L2-resident, gathers hit L2.
// Wave = 8 rows x 8 lanes; lane owns dword d (2 cols of the slice) and walks
// its row's edges serially, cv + gather prefetched one edge ahead (R6-style
// simple pipeline). No cross-lane reduce; float2 NT store per lane.
// ---------------------------------------------------------------------------
__global__ __launch_bounds__(256) void spmm_sliced_kernel(
    const unsigned* __restrict__ ys,     // [NSLICE][n_nodes][8] dwords
    const int* __restrict__ ptr,
    const int* __restrict__ col, const float* __restrict__ val,
    float* __restrict__ out, int n_nodes)
{
    const int bid  = blockIdx.x;
    const int pass = bid & 7;
    const int rblk = bid >> 3;
    const int w    = threadIdx.x >> 6;
    const int lane = threadIdx.x & 63;
    const int rl   = lane >> 3;          // row within wave's 8
    const int d    = lane & 7;           // dword within 32 B slice
    const int row  = (rblk << 5) + (w << 3) + rl;
    if (row >= n_nodes) return;

    const int s   = ptr[row];
    const int e   = ptr[row + 1];
    const int len = e - s;

    const unsigned* yp = ys + (size_t)pass * n_nodes * 8 + d;   // + c*8

    f32x2 acc; acc.x = 0.f; acc.y = 0.f;

    if (len > 0) {
        int      c0 = col[s];
        float    v0 = val[s];
        unsigned u0 = yp[(size_t)c0 * 8];
        for (int i = 1; i < len; ++i) {
            const int      c1 = col[s + i];          // prefetch cv(i)
            const float    v1 = val[s + i];
            const unsigned u1 = yp[(size_t)c1 * 8];  // issue gather(i)
            f32x2 t;  t.x  = bflo(u0); t.y = bfhi(u0);
            f32x2 vv; vv.x = v0;       vv.y = v0;
            acc += vv * t;                           // consume(i-1)
            u0 = u1; v0 = v1;
        }
        f32x2 t;  t.x  = bflo(u0); t.y = bfhi(u0);
        f32x2 vv; vv.x = v0;       vv.y = v0;
        acc += vv * t;
    }

    // out[row][pass*16 + d*2 .. +1]
    float* op = out + (size_t)row * D + pass * 16 + d * 2;
    __builtin_nontemporal_store(acc, reinterpret_cast<f32x2*>(op));
}

// ---------------------------------------------------------------------------
extern "C" void kernel_launch(void* const* d_in, const int* in_sizes, int n_in,
                              void* d_out, int out_size, void* d_ws, size_t ws_size,
                              hipStream_t stream)
{
    const float* x        = (const float*)d_in[0];
    const int*   edge_row = (const int*)  d_in[1];
    const int*   edge_col = (const int*)  d_in[2];
    const float* edge_val = (const float*)d_in[3];
    const float* W        = (const float*)d_in[4];
    float*       out      = (float*)d_out;

    const int n_nodes = in_sizes[0] / D;
    const int n_edges = in_sizes[1];
    const int ntiles  = (n_nodes + 15) / 16;

    // workspace: y_slice_major [8][n_nodes][16] bf16 = n_nodes*256 B | row_ptr
    unsigned* y   = (unsigned*)d_ws;
    int*      ptr = (int*)((char*)d_ws + (size_t)n_nodes * 256);

    // 1) y = bf16(x @ W)  (MFMA, slice-major store)
    gemm_mfma_kernel<<<512, 256, 0, stream>>>(x, W, y, n_nodes, ntiles);

    // 2) row_ptr
    {
        int blocks = (n_edges + 1 + 255) / 256;
        build_rowptr_kernel<<<blocks, 256, 0, stream>>>(edge_row, ptr, n_edges, n_nodes);
    }
    // 3) out = A @ y   (sliced, XCD-pinned)
    {
        int rblocks = (n_nodes + 31) / 32;
        int blocks  = rblocks * NSLICE;
        spmm_sliced_kernel<<<blocks, 256, 0, stream>>>((const unsigned*)y, ptr,
                                                       edge_col, edge_val,
                                                       out, n_nodes);
    }
}